// Round 4
// baseline (237.617 us; speedup 1.0000x reference)
//
#include <hip/hip_runtime.h>
#include <math.h>

#define DIM 1024

// Native clang vector type — __builtin_nontemporal_load/store require a
// scalar or native vector, not HIP_vector_type<float,4>.
typedef float vfloat4 __attribute__((ext_vector_type(4)));

// Fused kernel: every block redundantly computes
//   mask = DIM * softmax(mask_param) * _mask          (1024 channels)
// then applies its grid-stride slice of out = x * mask (float4-vectorized).
// Block 0 additionally writes the mask to the second output slot.
//
// R4 change (single variable): REGULAR loads + NT stores.
// Completes the NT 2x2: NT/NT=226.1, NT/reg=229.6, reg/NT=?
// Mechanism: nt loads bypass L1/L2 allocation -> no TCC-side read
// combining; the 6.29 TB/s float4-copy ceiling (m13) and the 6.7 TB/s
// harness fills both use regular cache-allocating accesses. L2 pollution
// is a non-issue (x is read-once, nothing else wants L2), so regular
// loads have no downside.
//
// History: R1 distant 4x unroll = +6.4 us; R2 barrier-free softmax
// prologue = neutral; R3 regular stores = +3.5 us (revert).
__global__ __launch_bounds__(256) void fused_mask_mul_kernel(
    const vfloat4* __restrict__ x,
    const vfloat4* __restrict__ mask_param4,  // 256 float4 = 1024 floats
    const vfloat4* __restrict__ mask_in4,     // 256 float4
    vfloat4* __restrict__ out,
    vfloat4* __restrict__ mask_out4,          // 256 float4 (output 1)
    int n4)
{
    const int t = threadIdx.x;               // 0..255
    const int l = t & 63;                    // lane
    const int w = t >> 6;                    // wave id in block

    // ---- wave-redundant softmax over 1024 channels, shuffle-only ----
    // Each lane reads 4 float4 columns: l, l+64, l+128, l+192.
    const vfloat4 q0 = mask_param4[l];
    const vfloat4 q1 = mask_param4[l + 64];
    const vfloat4 q2 = mask_param4[l + 128];
    const vfloat4 q3 = mask_param4[l + 192];

    float m = fmaxf(fmaxf(q0.x, q0.y), fmaxf(q0.z, q0.w));
    m = fmaxf(m, fmaxf(fmaxf(q1.x, q1.y), fmaxf(q1.z, q1.w)));
    m = fmaxf(m, fmaxf(fmaxf(q2.x, q2.y), fmaxf(q2.z, q2.w)));
    m = fmaxf(m, fmaxf(fmaxf(q3.x, q3.y), fmaxf(q3.z, q3.w)));
    #pragma unroll
    for (int o = 32; o > 0; o >>= 1) m = fmaxf(m, __shfl_xor(m, o, 64));

    vfloat4 e0, e1, e2, e3;
    e0.x = __expf(q0.x - m); e0.y = __expf(q0.y - m);
    e0.z = __expf(q0.z - m); e0.w = __expf(q0.w - m);
    e1.x = __expf(q1.x - m); e1.y = __expf(q1.y - m);
    e1.z = __expf(q1.z - m); e1.w = __expf(q1.w - m);
    e2.x = __expf(q2.x - m); e2.y = __expf(q2.y - m);
    e2.z = __expf(q2.z - m); e2.w = __expf(q2.w - m);
    e3.x = __expf(q3.x - m); e3.y = __expf(q3.y - m);
    e3.z = __expf(q3.z - m); e3.w = __expf(q3.w - m);

    float s = (e0.x + e0.y + e0.z + e0.w) + (e1.x + e1.y + e1.z + e1.w)
            + (e2.x + e2.y + e2.z + e2.w) + (e3.x + e3.y + e3.z + e3.w);
    #pragma unroll
    for (int o = 32; o > 0; o >>= 1) s += __shfl_xor(s, o, 64);

    const float scale = (float)DIM / s;      // PRUNE_RATE = 1.0

    // Thread t's own channels (4t..4t+3) are column t = l + 64*w -> e{w}.
    // w is wave-uniform; static select chain (no runtime array index).
    vfloat4 esel = (w == 0) ? e0 : (w == 1) ? e1 : (w == 2) ? e2 : e3;
    const vfloat4 mi = mask_in4[t];
    vfloat4 mv = esel * scale * mi;

    if (blockIdx.x == 0) mask_out4[t] = mv;

    // ---- grid-stride broadcast multiply: REGULAR loads, NT stores ----
    const int idx    = blockIdx.x * 256 + t;
    const int stride = gridDim.x * 256;      // multiple of 256 -> mask invariant
    for (int i = idx; i < n4; i += stride) {
        vfloat4 v = x[i];
        v *= mv;
        __builtin_nontemporal_store(v, &out[i]);
    }
}

extern "C" void kernel_launch(void* const* d_in, const int* in_sizes, int n_in,
                              void* d_out, int out_size, void* d_ws, size_t ws_size,
                              hipStream_t stream)
{
    const float* x          = (const float*)d_in[0];   // [8,4096,1024] fp32
    const float* mask_param = (const float*)d_in[1];   // [1024] fp32
    const float* mask_in    = (const float*)d_in[2];   // [1024] fp32 (ones)

    const int n = in_sizes[0];                         // 33554432
    float* out_xm   = (float*)d_out;                   // output 0
    float* out_mask = (float*)d_out + n;               // output 1 (1024 floats)

    const int n4 = n / 4;                              // 8388608
    const int blocks = 2048;                           // 16 float4 per thread
    fused_mask_mul_kernel<<<blocks, 256, 0, stream>>>(
        (const vfloat4*)x, (const vfloat4*)mask_param, (const vfloat4*)mask_in,
        (vfloat4*)out_xm, (vfloat4*)out_mask, n4);
}

// Round 5
// 225.979 us; speedup vs baseline: 1.0515x; 1.0515x over previous
//
#include <hip/hip_runtime.h>
#include <math.h>

#define DIM 1024

// Native clang vector type — __builtin_nontemporal_load/store require a
// scalar or native vector, not HIP_vector_type<float,4>.
typedef float vfloat4 __attribute__((ext_vector_type(4)));

// Fused kernel: every block redundantly computes
//   mask = DIM * softmax(mask_param) * _mask          (1024 channels)
// then applies its grid-stride slice of out = x * mask (float4-vectorized,
// NT loads + NT stores). Block 0 additionally writes the mask output.
//
// R5 change (single variable vs R2 best): explicit 1-deep prefetch
// pipeline in the streaming loop — issue load(i+1) BEFORE store(i).
// Mechanism: in the rolled loop, the store shares the vmcnt domain with
// the next iteration's load-wait; a conservative vmcnt(0) drains the
// store every iteration, capping per-wave MLP at ~1. Staggering makes a
// counted wait (old load only, store left in flight) the natural emission.
// R1 tested burst-grouping (4 loads then 4 stores, distant) and regressed;
// staggering was never tested.
//
// Evidence so far: NT/NT=226.1 > NT/reg=229.6 > reg/NT=237.6 (kernel
// visible at 82.4us, 2.44 TB/s, FETCH only 65.6MB -> allocating loads
// throttle issue, NOT BW-bound). Fills ~80us each bound the headline:
// headline = kernel + ~160us of harness poison fills.
__global__ __launch_bounds__(256) void fused_mask_mul_kernel(
    const vfloat4* __restrict__ x,
    const vfloat4* __restrict__ mask_param4,  // 256 float4 = 1024 floats
    const vfloat4* __restrict__ mask_in4,     // 256 float4
    vfloat4* __restrict__ out,
    vfloat4* __restrict__ mask_out4,          // 256 float4 (output 1)
    int n4)
{
    const int t = threadIdx.x;               // 0..255
    const int l = t & 63;                    // lane
    const int w = t >> 6;                    // wave id in block

    // ---- wave-redundant softmax over 1024 channels, shuffle-only ----
    // Each lane reads 4 float4 columns: l, l+64, l+128, l+192.
    const vfloat4 q0 = mask_param4[l];
    const vfloat4 q1 = mask_param4[l + 64];
    const vfloat4 q2 = mask_param4[l + 128];
    const vfloat4 q3 = mask_param4[l + 192];

    float m = fmaxf(fmaxf(q0.x, q0.y), fmaxf(q0.z, q0.w));
    m = fmaxf(m, fmaxf(fmaxf(q1.x, q1.y), fmaxf(q1.z, q1.w)));
    m = fmaxf(m, fmaxf(fmaxf(q2.x, q2.y), fmaxf(q2.z, q2.w)));
    m = fmaxf(m, fmaxf(fmaxf(q3.x, q3.y), fmaxf(q3.z, q3.w)));
    #pragma unroll
    for (int o = 32; o > 0; o >>= 1) m = fmaxf(m, __shfl_xor(m, o, 64));

    vfloat4 e0, e1, e2, e3;
    e0.x = __expf(q0.x - m); e0.y = __expf(q0.y - m);
    e0.z = __expf(q0.z - m); e0.w = __expf(q0.w - m);
    e1.x = __expf(q1.x - m); e1.y = __expf(q1.y - m);
    e1.z = __expf(q1.z - m); e1.w = __expf(q1.w - m);
    e2.x = __expf(q2.x - m); e2.y = __expf(q2.y - m);
    e2.z = __expf(q2.z - m); e2.w = __expf(q2.w - m);
    e3.x = __expf(q3.x - m); e3.y = __expf(q3.y - m);
    e3.z = __expf(q3.z - m); e3.w = __expf(q3.w - m);

    float s = (e0.x + e0.y + e0.z + e0.w) + (e1.x + e1.y + e1.z + e1.w)
            + (e2.x + e2.y + e2.z + e2.w) + (e3.x + e3.y + e3.z + e3.w);
    #pragma unroll
    for (int o = 32; o > 0; o >>= 1) s += __shfl_xor(s, o, 64);

    const float scale = (float)DIM / s;      // PRUNE_RATE = 1.0

    // Thread t's own channels (4t..4t+3) are column t = l + 64*w -> e{w}.
    // w is wave-uniform; static select chain (no runtime array index).
    vfloat4 esel = (w == 0) ? e0 : (w == 1) ? e1 : (w == 2) ? e2 : e3;
    const vfloat4 mi = mask_in4[t];
    vfloat4 mv = esel * scale * mi;

    if (blockIdx.x == 0) mask_out4[t] = mv;

    // ---- grid-stride broadcast multiply: NT/NT, 1-deep prefetch ----
    // idx < stride always (grid covers stride exactly), n4 % stride == 0
    // in the bench shape; general guards kept for safety.
    const int idx    = blockIdx.x * 256 + t;
    const int stride = gridDim.x * 256;      // multiple of 256 -> mask invariant
    int i = idx;
    if (i < n4) {
        vfloat4 cur = __builtin_nontemporal_load(&x[i]);
        for (; i + stride < n4; i += stride) {
            vfloat4 nxt = __builtin_nontemporal_load(&x[i + stride]);
            vfloat4 v = cur * mv;
            __builtin_nontemporal_store(v, &out[i]);
            cur = nxt;
        }
        vfloat4 v = cur * mv;
        __builtin_nontemporal_store(v, &out[i]);
    }
}

extern "C" void kernel_launch(void* const* d_in, const int* in_sizes, int n_in,
                              void* d_out, int out_size, void* d_ws, size_t ws_size,
                              hipStream_t stream)
{
    const float* x          = (const float*)d_in[0];   // [8,4096,1024] fp32
    const float* mask_param = (const float*)d_in[1];   // [1024] fp32
    const float* mask_in    = (const float*)d_in[2];   // [1024] fp32 (ones)

    const int n = in_sizes[0];                         // 33554432
    float* out_xm   = (float*)d_out;                   // output 0
    float* out_mask = (float*)d_out + n;               // output 1 (1024 floats)

    const int n4 = n / 4;                              // 8388608
    const int blocks = 2048;                           // 16 float4 per thread
    fused_mask_mul_kernel<<<blocks, 256, 0, stream>>>(
        (const vfloat4*)x, (const vfloat4*)mask_param, (const vfloat4*)mask_in,
        (vfloat4*)out_xm, (vfloat4*)out_mask, n4);
}